// Round 4
// baseline (159.601 us; speedup 1.0000x reference)
//
#include <hip/hip_runtime.h>
#include <hip/hip_bf16.h>
#include <math.h>

// ---------------- problem constants ----------------
constexpr int BS   = 512;
constexpr int DM   = 768;
constexpr int NBS  = 1536;   // BS * NSENT
constexpr int NPOS = 300;    // HIST*H*W
constexpr int LIN  = 5184;   // FM * 9 * 9
constexpr int KSPLIT = 9, KCH = 576;    // 9*576 = 5184

typedef __attribute__((ext_vector_type(8))) short bf16x8;
typedef __attribute__((ext_vector_type(4))) short s16x4;
typedef __attribute__((ext_vector_type(4))) float f32x4;

static __device__ __forceinline__ short f2bf(float f) {
    unsigned u = __float_as_uint(f);
    unsigned r = (u + 0x7FFFu + ((u >> 16) & 1u)) >> 16;
    return (short)r;
}
static __device__ __forceinline__ float bf2f_lo(unsigned u) {   // low short
    return __uint_as_float(u << 16);
}
static __device__ __forceinline__ float bf2f_hi(unsigned u) {   // high short
    return __uint_as_float(u & 0xFFFF0000u);
}

// ---------------- workspace layout (float offsets) ----------------
constexpr size_t OFF_RD   = 0;            // 26*768 fp32 (rows 0..24 rowdot, row 25 = bv@W2)
constexpr size_t OFF_FL   = 19968;        // 64 (int)
constexpr size_t OFF_DT   = 20032;        // fp32 [1536][64]
constexpr size_t OFF_W2T  = 118336;       // bf16 [768][256] -> 49152 floats
constexpr size_t OFF_WVH  = 167488;       // bf16 [768][256] -> 49152
constexpr size_t OFF_WCT  = 216640;       // bf16 [768][768] -> 294912
constexpr size_t OFF_PH   = 511552;       // bf16 [64][768]  -> 24576
constexpr size_t OFF_AB   = 536128;       // bf16 [256][5184] -> 663552
constexpr size_t OFF_XKH  = 1199680;      // bf16 [1536][768] -> 589824
constexpr size_t OFF_XVH  = 1789504;      // bf16 [1536][768] -> 589824
constexpr size_t OFF_VWH  = 2379328;      // bf16 [1536][768] -> 589824
constexpr size_t OFF_YH   = 2969152;      // bf16 [512][5184] -> 1327104
constexpr size_t OFF_PART = 4296256;      // fp32 [9][512][256] ; end ~ 5.48M floats (21.9MB)

// ================= k1: single-pass temb (+ all prep as extra blocks) =========
// blocks 0..1535   : per-(b,s) token softmax + weighted sums -> XKH, XVH (bf16)
// blocks 1536..1997: prep (W2T, WVH, AB, PH, RD, flags)
__global__ __launch_bounds__(512) void k1_main(
    const float* __restrict__ temb, const float* __restrict__ Wks,
    const float* __restrict__ Wvs, const float* __restrict__ conv_w,
    const float* __restrict__ sprite, const float* __restrict__ Wk,
    const float* __restrict__ Wv, const float* __restrict__ bv,
    const float* __restrict__ a1, const float* __restrict__ v1,
    short* __restrict__ XKH, short* __restrict__ XVH,
    short* __restrict__ W2T, short* __restrict__ WVH, short* __restrict__ AB,
    short* __restrict__ PH, float* __restrict__ RD, int* __restrict__ FL)
{
    __shared__ float buf[36 * 768];     // 110.6 KB
    __shared__ float sco[4][40];        // sk, sv, swk, swv
    int tid = threadIdx.x, bx = blockIdx.x;

    if (bx < NBS) {
        int bs = bx;
        // ---- stage full (b,s) row: 6912 float4 ----
        const float4* src4 = (const float4*)temb + (size_t)bs * 6912;
        float4 r[14];
        #pragma unroll
        for (int c = 0; c < 14; ++c) {
            int i = c * 512 + tid;
            if (c < 13 || tid < 256) r[c] = src4[i];
        }
        #pragma unroll
        for (int c = 0; c < 14; ++c) {
            int i = c * 512 + tid;
            if (c < 13 || tid < 256) *(float4*)&buf[4 * i] = r[c];
        }
        __syncthreads();
        // ---- scores: wave w handles tokens w, w+8, ... ----
        int w = tid >> 6, lane = tid & 63;
        const float4* wk4 = (const float4*)Wks;
        const float4* wv4 = (const float4*)Wvs;
        for (int t = w; t < 36; t += 8) {
            float pk = 0.f, pv = 0.f;
            #pragma unroll
            for (int rd = 0; rd < 3; ++rd) {
                int i4 = rd * 64 + lane;
                float4 x = *(const float4*)&buf[t * 768 + i4 * 4];
                float4 a = wk4[i4], b = wv4[i4];
                pk += x.x * a.x + x.y * a.y + x.z * a.z + x.w * a.w;
                pv += x.x * b.x + x.y * b.y + x.z * b.z + x.w * b.w;
            }
            #pragma unroll
            for (int off = 32; off; off >>= 1) {
                pk += __shfl_down(pk, off);
                pv += __shfl_down(pv, off);
            }
            if (lane == 0) { sco[0][t] = pk; sco[1][t] = pv; }
        }
        __syncthreads();
        // ---- exact softmax over 36 tokens (waves 0,1 for k,v) ----
        if (w < 2) {
            float s = (lane < 36) ? sco[w][lane] : -INFINITY;
            float m = s;
            #pragma unroll
            for (int off = 32; off; off >>= 1) m = fmaxf(m, __shfl_xor(m, off));
            float e = (lane < 36) ? expf(s - m) : 0.f;
            float z = e;
            #pragma unroll
            for (int off = 32; off; off >>= 1) z += __shfl_xor(z, off);
            if (lane < 36) sco[2 + w][lane] = e / z;
        }
        __syncthreads();
        // ---- weighted sums: thread owns 2 d-columns across all 36 tokens ----
        if (tid < 384) {
            float k0 = 0.f, k1v = 0.f, v0 = 0.f, v1v = 0.f;
            #pragma unroll
            for (int t = 0; t < 36; ++t) {
                float2 x = *(const float2*)&buf[t * 768 + 2 * tid];
                float wkt = sco[2][t], wvt = sco[3][t];
                k0 += wkt * x.x; k1v += wkt * x.y;
                v0 += wvt * x.x; v1v += wvt * x.y;
            }
            ushort2 hk = { (unsigned short)f2bf(k0), (unsigned short)f2bf(k1v) };
            ushort2 hv = { (unsigned short)f2bf(v0), (unsigned short)f2bf(v1v) };
            *(ushort2*)&XKH[(size_t)bs * 768 + 2 * tid] = hk;
            *(ushort2*)&XVH[(size_t)bs * 768 + 2 * tid] = hv;
        }
        return;
    }

    // ================= prep blocks =================
    int id = bx - NBS;
    float (*tile)[65] = (float(*)[65])buf;
    if (id < 48) {
        // W2T[n=(t4*3+j)*64+f][c] = conv_w[t4][j*256+c][f]  (bf16, K-major over c)
        int p = id >> 2, cq = id & 3;
        int t4 = p / 3, j = p - t4 * 3;
        int c0 = cq * 64;
        #pragma unroll
        for (int it = 0; it < 8; ++it) {
            int idx = it * 512 + tid; int ci = idx >> 6, f = idx & 63;
            tile[ci][f] = conv_w[(size_t)(t4 * 768 + j * 256 + c0 + ci) * 64 + f];
        }
        __syncthreads();
        #pragma unroll
        for (int it = 0; it < 8; ++it) {
            int idx = it * 512 + tid; int f = idx >> 6, ci = idx & 63;
            W2T[(size_t)((t4 * 3 + j) * 64 + f) * 256 + c0 + ci] = f2bf(tile[ci][f]);
        }
    } else if (id < 60) {
        // WVH = bf16(Wv) row-major [768][256]
        int b2 = id - 48;
        #pragma unroll
        for (int it = 0; it < 8; ++it) {
            int i4 = b2 * 4096 + it * 512 + tid;
            float4 v = ((const float4*)Wv)[i4];
            s16x4 h = { f2bf(v.x), f2bf(v.y), f2bf(v.z), f2bf(v.w) };
            *(s16x4*)&WVH[4 * i4] = h;
        }
    } else if (id < 384) {
        // AB[n][k]: n<128 -> a1 col n ; n>=128 -> v1 col n-128  (both 5184x128)
        int q = id - 60; int kt = q % 81, nt = q / 81;
        const float* src = (nt < 2) ? a1 : v1;
        int col0 = (nt & 1) * 64;
        #pragma unroll
        for (int it = 0; it < 8; ++it) {
            int idx = it * 512 + tid; int ki = idx >> 6, ni = idx & 63;
            tile[ki][ni] = src[(size_t)(kt * 64 + ki) * 128 + col0 + ni];
        }
        __syncthreads();
        #pragma unroll
        for (int it = 0; it < 8; ++it) {
            int idx = it * 512 + tid; int ni = idx >> 6, ki = idx & 63;
            AB[(size_t)(nt * 64 + ni) * 5184 + kt * 64 + ki] = f2bf(tile[ki][ni]);
        }
    } else if (id < 422) {
        // PH[o][d] = bf16( sum_c sprite[o][c]*Wk[d][c] ),  o<25 (rows 25..63 unused)
        int g = (id - 384) * 512 + tid;
        if (g < 19200) {
            int o = g / 768, d = g - o * 768;
            const float* sp = sprite + o * 256;
            const float* wr = Wk + (size_t)d * 256;
            float s = 0.f;
            for (int c = 0; c < 256; ++c) s += sp[c] * wr[c];
            PH[(size_t)o * 768 + d] = f2bf(s);
        }
    } else if (id < 461) {
        // RD[o][n]: o<25 rowdot rows (sprite), o==25 -> bv@W2
        int g = (id - 422) * 512 + tid;
        if (g < 19968) {
            int o = g / 768, n = g - o * 768;
            int tap = n >> 6, f = n & 63; int t4 = tap / 3, j = tap - t4 * 3;
            const float* sp = (o < 25) ? (sprite + o * 256) : bv;
            float s = 0.f;
            for (int e = 0; e < 256; ++e)
                s += sp[e] * conv_w[(size_t)(t4 * 768 + j * 256 + e) * 64 + f];
            RD[g] = s;
        }
    } else {
        if (tid < 25) {
            float s = 0.f;
            for (int c = 0; c < 256; ++c) s += sprite[tid * 256 + c];
            FL[tid] = (s != 0.0f) ? 1 : 0;
        }
    }
}

// ---------------- generic MFMA bf16 GEMM: A[M][K] rm, B[N][K] K-major --------
template<int BIAS, int OUTBF>
__global__ __launch_bounds__(256) void gemm_mfma(
    const short* __restrict__ A, const short* __restrict__ B,
    const float* __restrict__ bias, void* __restrict__ Cout,
    int K, int ldc, int klen, size_t czstride)
{
    __shared__ short As[64][40];
    __shared__ short Bs[64][40];
    int tid = threadIdx.x;
    int bm = blockIdx.x * 64, bn = blockIdx.y * 64;
    int wid = tid >> 6, lane = tid & 63;
    int wm = (wid >> 1) * 32, wn = (wid & 1) * 32;
    int l15 = lane & 15, lg = lane >> 4;

    f32x4 zero = {0.f, 0.f, 0.f, 0.f};
    f32x4 acc00 = zero, acc01 = zero, acc10 = zero, acc11 = zero;

    int srow = tid >> 2, kch = (tid & 3) * 8;
    const short* Ap = A + (size_t)(bm + srow) * K + kch + (size_t)blockIdx.z * klen;
    const short* Bp = B + (size_t)(bn + srow) * K + kch + (size_t)blockIdx.z * klen;

    for (int kt = 0; kt < klen; kt += 32) {
        bf16x8 aval = *(const bf16x8*)(Ap + kt);
        bf16x8 bval = *(const bf16x8*)(Bp + kt);
        *(bf16x8*)&As[srow][kch] = aval;
        *(bf16x8*)&Bs[srow][kch] = bval;
        __syncthreads();
        bf16x8 af0 = *(const bf16x8*)&As[wm + l15][lg * 8];
        bf16x8 af1 = *(const bf16x8*)&As[wm + 16 + l15][lg * 8];
        bf16x8 bg0 = *(const bf16x8*)&Bs[wn + l15][lg * 8];
        bf16x8 bg1 = *(const bf16x8*)&Bs[wn + 16 + l15][lg * 8];
        acc00 = __builtin_amdgcn_mfma_f32_16x16x32_bf16(af0, bg0, acc00, 0, 0, 0);
        acc01 = __builtin_amdgcn_mfma_f32_16x16x32_bf16(af0, bg1, acc01, 0, 0, 0);
        acc10 = __builtin_amdgcn_mfma_f32_16x16x32_bf16(af1, bg0, acc10, 0, 0, 0);
        acc11 = __builtin_amdgcn_mfma_f32_16x16x32_bf16(af1, bg1, acc11, 0, 0, 0);
        __syncthreads();
    }

    float* Cf = (float*)Cout + (size_t)blockIdx.z * czstride;
    short* Ch = (short*)Cout;
    #pragma unroll
    for (int i = 0; i < 2; ++i) {
        f32x4 arow0 = (i == 0) ? acc00 : acc10;
        f32x4 arow1 = (i == 0) ? acc01 : acc11;
        #pragma unroll
        for (int j = 0; j < 2; ++j) {
            f32x4 a = (j == 0) ? arow0 : arow1;
            int col = bn + wn + j * 16 + l15;
            float bb = BIAS ? bias[col] : 0.f;
            #pragma unroll
            for (int r = 0; r < 4; ++r) {
                int row = bm + wm + i * 16 + lg * 4 + r;
                float v = a[r] + bb;
                if (OUTBF) Ch[(size_t)row * ldc + col] = f2bf(v);
                else       Cf[(size_t)row * ldc + col] = v;
            }
        }
    }
}

// ================= k3: fused VW gemm (by<12) + DT gemm (by==12), K=768 =======
__global__ __launch_bounds__(256) void k3_vwdt(
    const short* __restrict__ XVH, const short* __restrict__ WCT,
    const float* __restrict__ bvW2, short* __restrict__ VWH,
    const short* __restrict__ XKH, const short* __restrict__ PH,
    float* __restrict__ DT)
{
    __shared__ short As[64][40];
    __shared__ short Bs[64][40];
    int tid = threadIdx.x;
    bool isdt = (blockIdx.y == 12);
    const short* A = isdt ? XKH : XVH;
    const short* B = isdt ? PH  : WCT;
    int bm = blockIdx.x * 64, bn = isdt ? 0 : blockIdx.y * 64;
    int wid = tid >> 6, lane = tid & 63;
    int wm = (wid >> 1) * 32, wn = (wid & 1) * 32;
    int l15 = lane & 15, lg = lane >> 4;

    f32x4 zero = {0.f, 0.f, 0.f, 0.f};
    f32x4 acc00 = zero, acc01 = zero, acc10 = zero, acc11 = zero;

    int srow = tid >> 2, kch = (tid & 3) * 8;
    const short* Ap = A + (size_t)(bm + srow) * 768 + kch;
    const short* Bp = B + (size_t)(bn + srow) * 768 + kch;

    for (int kt = 0; kt < 768; kt += 32) {
        bf16x8 aval = *(const bf16x8*)(Ap + kt);
        bf16x8 bval = *(const bf16x8*)(Bp + kt);
        *(bf16x8*)&As[srow][kch] = aval;
        *(bf16x8*)&Bs[srow][kch] = bval;
        __syncthreads();
        bf16x8 af0 = *(const bf16x8*)&As[wm + l15][lg * 8];
        bf16x8 af1 = *(const bf16x8*)&As[wm + 16 + l15][lg * 8];
        bf16x8 bg0 = *(const bf16x8*)&Bs[wn + l15][lg * 8];
        bf16x8 bg1 = *(const bf16x8*)&Bs[wn + 16 + l15][lg * 8];
        acc00 = __builtin_amdgcn_mfma_f32_16x16x32_bf16(af0, bg0, acc00, 0, 0, 0);
        acc01 = __builtin_amdgcn_mfma_f32_16x16x32_bf16(af0, bg1, acc01, 0, 0, 0);
        acc10 = __builtin_amdgcn_mfma_f32_16x16x32_bf16(af1, bg0, acc10, 0, 0, 0);
        acc11 = __builtin_amdgcn_mfma_f32_16x16x32_bf16(af1, bg1, acc11, 0, 0, 0);
        __syncthreads();
    }

    #pragma unroll
    for (int i = 0; i < 2; ++i) {
        f32x4 arow0 = (i == 0) ? acc00 : acc10;
        f32x4 arow1 = (i == 0) ? acc01 : acc11;
        #pragma unroll
        for (int j = 0; j < 2; ++j) {
            f32x4 a = (j == 0) ? arow0 : arow1;
            int col = bn + wn + j * 16 + l15;
            #pragma unroll
            for (int r = 0; r < 4; ++r) {
                int row = bm + wm + i * 16 + lg * 4 + r;
                if (isdt) DT[(size_t)row * 64 + col] = a[r];
                else      VWH[(size_t)row * 768 + col] = f2bf(a[r] + bvW2[col]);
            }
        }
    }
}

// ================= k4: wts + factored conv + transpose-flatten + lrelu =======
__global__ __launch_bounds__(512) void k4_y(
    const int* __restrict__ state, const float* __restrict__ dt,
    const int* __restrict__ flags, const short* __restrict__ VWH,
    const float* __restrict__ rowdot, const float* __restrict__ conv_b,
    short* __restrict__ y)
{
    int b = blockIdx.x, tid = threadIdx.x;
    __shared__ float s_vW[3 * 768];
    __shared__ float s_w[3][NPOS + 4];
    __shared__ int   s_avt[NPOS + 4];
    __shared__ float s_y[81 * 65];

    // unpack bf16 vW rows (3*768 = 1152 uints)
    const unsigned* vr = (const unsigned*)(VWH + (size_t)b * 3 * 768);
    for (int i = tid; i < 1152; i += 512) {
        unsigned u = vr[i];
        s_vW[2 * i]     = bf2f_lo(u);
        s_vW[2 * i + 1] = bf2f_hi(u);
    }

    for (int code = tid; code < NPOS; code += 512) {
        const int* st = state + ((size_t)b * NPOS + code) * 4;
        int o0 = st[0], o1 = st[1], o2 = st[2], avi = st[3];
        int cnt = flags[o0] + flags[o1] + flags[o2];
        s_avt[code] = avi;
        float w0 = 0.f, w1 = 0.f, w2 = 0.f;
        if (cnt > 0) {
            const float* d0 = dt + (size_t)b * 192;   // [3][64]
            float inv = 1.0f / (16.0f * (float)cnt);
            float q0 = (d0[o0]       + d0[o1]       + d0[o2])       * inv;
            float q1 = (d0[64 + o0]  + d0[64 + o1]  + d0[64 + o2])  * inv;
            float q2 = (d0[128 + o0] + d0[128 + o1] + d0[128 + o2]) * inv;
            float m = fmaxf(q0, fmaxf(q1, q2));
            float e0 = expf(q0 - m), e1 = expf(q1 - m), e2 = expf(q2 - m);
            float is = 1.0f / (6.0f * (e0 + e1 + e2));   // folds att/3 and st/2
            w0 = e0 * is; w1 = e1 * is; w2 = e2 * is;
        }
        s_w[0][code] = w0; s_w[1][code] = w1; s_w[2][code] = w2;
    }
    __syncthreads();

    int f = tid & 63;
    float cb = conv_b[f];
    for (int p = tid >> 6; p < 81; p += 8) {
        int oh = p / 9, ow = p - oh * 9;
        float acc = cb;
        #pragma unroll
        for (int kh = 0; kh < 2; ++kh)
        #pragma unroll
        for (int kw = 0; kw < 2; ++kw) {
            int bc = 3 * ((oh + kh) * 10 + (ow + kw));
            int tbase = ((kh * 2 + kw) * 3) * 64 + f;
            #pragma unroll
            for (int j = 0; j < 3; ++j) {
                int code = bc + j;
                int tf = tbase + j * 64;
                acc += s_w[0][code] * s_vW[tf]
                     + s_w[1][code] * s_vW[768 + tf]
                     + s_w[2][code] * s_vW[2 * 768 + tf];
                acc += 0.5f * rowdot[(size_t)s_avt[code] * 768 + tf];
            }
        }
        acc = acc > 0.f ? acc : 0.01f * acc;
        s_y[p * 65 + f] = acc;
    }
    __syncthreads();
    for (int i = tid; i < LIN; i += 512) {
        int ff = i / 81, pp = i - ff * 81;
        y[(size_t)b * LIN + i] = f2bf(s_y[pp * 65 + ff]);
    }
}

// ================= k6: split-K reduce + layer2 + heads =======================
__global__ __launch_bounds__(128) void k6_heads(
    const float* __restrict__ PART, const float* __restrict__ a1b,
    const float* __restrict__ v1b, const int* __restrict__ action,
    const float* __restrict__ a2, const float* __restrict__ a2b,
    const float* __restrict__ a3, const float* __restrict__ a3b,
    const float* __restrict__ v2, const float* __restrict__ v2b,
    const float* __restrict__ v3, const float* __restrict__ v3b,
    float* __restrict__ out)
{
    int b = blockIdx.x, tid = threadIdx.x;
    __shared__ float h1a[128], h1v[128], h2a[128], red[128];
    __shared__ float lg[5];
    float sa0 = a1b[tid], sv0 = v1b[tid];
    const float* pb = PART + (size_t)b * 256;
    for (int z = 0; z < KSPLIT; ++z) {
        sa0 += pb[(size_t)z * (BS * 256) + tid];
        sv0 += pb[(size_t)z * (BS * 256) + 128 + tid];
    }
    h1a[tid] = sa0 > 0.f ? sa0 : 0.01f * sa0;
    h1v[tid] = sv0 > 0.f ? sv0 : 0.01f * sv0;
    __syncthreads();
    float sa = a2b[tid], sv = v2b[tid];
    for (int k = 0; k < 128; ++k) {
        sa += h1a[k] * a2[k * 128 + tid];
        sv += h1v[k] * v2[k * 128 + tid];
    }
    sa = sa > 0.f ? sa : 0.01f * sa;
    sv = sv > 0.f ? sv : 0.01f * sv;
    h2a[tid] = sa;
    red[tid] = sv * v3[tid];
    __syncthreads();
    for (int s = 64; s > 0; s >>= 1) {
        if (tid < s) red[tid] += red[tid + s];
        __syncthreads();
    }
    if (tid < 5) {
        float l = a3b[tid];
        for (int k = 0; k < 128; ++k) l += h2a[k] * a3[k * 5 + tid];
        lg[tid] = l;
    }
    __syncthreads();
    if (tid == 0) {
        float m = lg[0];
        for (int j2 = 1; j2 < 5; ++j2) m = fmaxf(m, lg[j2]);
        float se = 0.f;
        for (int j2 = 0; j2 < 5; ++j2) se += expf(lg[j2] - m);
        float lse = m + logf(se);
        int act = action[b];
        float ent = 0.f;
        for (int j2 = 0; j2 < 5; ++j2) {
            float lp = lg[j2] - lse;
            ent -= expf(lp) * lp;
        }
        out[b]        = lg[act] - lse;
        out[512 + b]  = red[0] + v3b[0];
        out[1024 + b] = ent;
    }
}

// ---------------- launch ----------------
extern "C" void kernel_launch(void* const* d_in, const int* in_sizes, int n_in,
                              void* d_out, int out_size, void* d_ws, size_t ws_size,
                              hipStream_t stream)
{
    const int*   state  = (const int*)d_in[0];
    const int*   action = (const int*)d_in[1];
    const float* temb   = (const float*)d_in[2];
    const float* sprite = (const float*)d_in[3];
    const float* conv_w = (const float*)d_in[4];
    const float* conv_b = (const float*)d_in[5];
    const float* Wk     = (const float*)d_in[6];
    const float* Wks    = (const float*)d_in[8];
    const float* Wv     = (const float*)d_in[10];
    const float* bv     = (const float*)d_in[11];
    const float* Wvs    = (const float*)d_in[12];
    const float* a1     = (const float*)d_in[14];
    const float* a1b    = (const float*)d_in[15];
    const float* a2     = (const float*)d_in[16];
    const float* a2b    = (const float*)d_in[17];
    const float* a3     = (const float*)d_in[18];
    const float* a3b    = (const float*)d_in[19];
    const float* v1     = (const float*)d_in[20];
    const float* v1b    = (const float*)d_in[21];
    const float* v2     = (const float*)d_in[22];
    const float* v2b    = (const float*)d_in[23];
    const float* v3     = (const float*)d_in[24];
    const float* v3b    = (const float*)d_in[25];
    (void)in_sizes; (void)n_in; (void)out_size; (void)ws_size;

    float* ws  = (float*)d_ws;
    float* RD  = ws + OFF_RD;
    float* bvW2= RD + 25 * 768;
    int*   FL  = (int*)(ws + OFF_FL);
    float* DT  = ws + OFF_DT;
    short* W2T = (short*)(ws + OFF_W2T);
    short* WVH = (short*)(ws + OFF_WVH);
    short* WCT = (short*)(ws + OFF_WCT);
    short* PH  = (short*)(ws + OFF_PH);
    short* AB  = (short*)(ws + OFF_AB);
    short* XKH = (short*)(ws + OFF_XKH);
    short* XVH = (short*)(ws + OFF_XVH);
    short* VWH = (short*)(ws + OFF_VWH);
    short* YH  = (short*)(ws + OFF_YH);
    float* PART= ws + OFF_PART;
    float* out = (float*)d_out;

    // 1) single-pass temb + all prep
    k1_main<<<1998, 512, 0, stream>>>(temb, Wks, Wvs, conv_w, sprite, Wk, Wv, bv,
                                      a1, v1, XKH, XVH, W2T, WVH, AB, PH, RD, FL);
    // 2) WCT[tf][d] = sum_c W2[tf][c]*Wv[d][c]   (768x768, K=256) -> bf16
    gemm_mfma<0,1><<<dim3(12,12,1),256,0,stream>>>(W2T, WVH, nullptr, WCT, 256, 768, 256, 0);
    // 3) VWH = XVH@WCT^T + bv@W2 (bf16)  ||  DT = XKH@PH^T (fp32)
    k3_vwdt<<<dim3(24,13,1),256,0,stream>>>(XVH, WCT, bvW2, VWH, XKH, PH, DT);
    // 4) conv + flatten
    k4_y<<<BS, 512, 0, stream>>>(state, DT, FL, VWH, RD, conv_b, YH);
    // 5) layer-1 split-K GEMM
    gemm_mfma<0,0><<<dim3(8,4,KSPLIT),256,0,stream>>>(YH, AB, nullptr, PART, 5184, 256, KCH, (size_t)BS*256);
    // 6) reduce + heads
    k6_heads<<<BS, 128, 0, stream>>>(PART, a1b, v1b, action, a2, a2b, a3, a3b,
                                     v2, v2b, v3, v3b, out);
}

// Round 5
// 130.975 us; speedup vs baseline: 1.2186x; 1.2186x over previous
//
#include <hip/hip_runtime.h>
#include <hip/hip_bf16.h>
#include <math.h>

// ---------------- problem constants ----------------
constexpr int BS   = 512;
constexpr int DM   = 768;
constexpr int NBS  = 1536;   // BS * NSENT
constexpr int NPOS = 300;    // HIST*H*W
constexpr int LIN  = 5184;   // FM * 9 * 9
constexpr int KSPLIT = 9, KCH = 576;    // 9*576 = 5184
constexpr int NROW = 55296;  // NBS * 36 token rows

typedef __attribute__((ext_vector_type(8))) short bf16x8;
typedef __attribute__((ext_vector_type(4))) short s16x4;
typedef __attribute__((ext_vector_type(4))) float f32x4;

static __device__ __forceinline__ short f2bf(float f) {
    unsigned u = __float_as_uint(f);
    unsigned r = (u + 0x7FFFu + ((u >> 16) & 1u)) >> 16;
    return (short)r;
}
static __device__ __forceinline__ float bf2f_lo(unsigned u) { return __uint_as_float(u << 16); }
static __device__ __forceinline__ float bf2f_hi(unsigned u) { return __uint_as_float(u & 0xFFFF0000u); }

// ---------------- workspace layout (float offsets) ----------------
constexpr size_t OFF_RD   = 0;            // 26*768 fp32 (0..24 rowdot, 25 = bv@W2)
constexpr size_t OFF_FL   = 19968;        // 64 (int)
constexpr size_t OFF_DT   = 20032;        // fp32 [1536][64]
constexpr size_t OFF_W2T  = 118336;       // bf16 [768][256] -> 49152 floats
constexpr size_t OFF_WVH  = 167488;       // bf16 [768][256] -> 49152
constexpr size_t OFF_WCT  = 216640;       // bf16 [768][768] -> 294912
constexpr size_t OFF_PH   = 511552;       // bf16 [64][768]  -> 24576
constexpr size_t OFF_AB   = 536128;       // bf16 [256][5184] -> 663552
constexpr size_t OFF_SK   = 1199680;      // 55296 fp32
constexpr size_t OFF_SV   = 1254976;      // 55296 fp32
constexpr size_t OFF_XKH  = 1310272;      // bf16 [1536][768] -> 589824
constexpr size_t OFF_XVH  = 1900096;      // bf16 [1536][768] -> 589824
constexpr size_t OFF_VWH  = 2489920;      // bf16 [1536][768] -> 589824
constexpr size_t OFF_YH   = 3079744;      // bf16 [512][5184] -> 1327104
constexpr size_t OFF_PART = 4406848;      // fp32 [9][512][256]; end 5586496 (~22.3MB)

// ======== k1: token scores (pass 1, streaming) + all prep as extra blocks ====
// blocks 0..13823  : 4 waves each, wave computes one (b,s,t) score pair
// blocks 13824..   : prep (W2T, WVH, AB, PH, RD, flags)
__global__ __launch_bounds__(256) void k1_scores_prep(
    const float* __restrict__ temb, const float* __restrict__ Wks,
    const float* __restrict__ Wvs, const float* __restrict__ conv_w,
    const float* __restrict__ sprite, const float* __restrict__ Wk,
    const float* __restrict__ Wv, const float* __restrict__ bv,
    const float* __restrict__ a1, const float* __restrict__ v1,
    float* __restrict__ SK, float* __restrict__ SV,
    short* __restrict__ W2T, short* __restrict__ WVH, short* __restrict__ AB,
    short* __restrict__ PH, float* __restrict__ RD, int* __restrict__ FL)
{
    __shared__ float tile[64][65];
    int tid = threadIdx.x, bx = blockIdx.x;

    if (bx < 13824) {
        int wid = tid >> 6, lane = tid & 63;
        size_t r = (size_t)bx * 4 + wid;          // row over 55296
        const float4* row = (const float4*)temb + r * 192;
        const float4* k4 = (const float4*)Wks;
        const float4* v4 = (const float4*)Wvs;
        float pk = 0.f, pv = 0.f;
        #pragma unroll
        for (int i = 0; i < 3; ++i) {
            int d4 = lane + 64 * i;
            float4 x = row[d4];
            float4 wk = k4[d4], wv = v4[d4];
            pk += x.x * wk.x + x.y * wk.y + x.z * wk.z + x.w * wk.w;
            pv += x.x * wv.x + x.y * wv.y + x.z * wv.z + x.w * wv.w;
        }
        #pragma unroll
        for (int off = 32; off; off >>= 1) {
            pk += __shfl_down(pk, off);
            pv += __shfl_down(pv, off);
        }
        if (lane == 0) { SK[r] = pk; SV[r] = pv; }
        return;
    }

    // ---------------- prep blocks ----------------
    int id = bx - 13824;
    if (id < 48) {
        // W2T[n=(t4*3+j)*64+f][c] = conv_w[t4][j*256+c][f]  (bf16, K-major over c)
        int p = id >> 2, cq = id & 3;
        int t4 = p / 3, j = p - t4 * 3;
        int c0 = cq * 64;
        #pragma unroll
        for (int it = 0; it < 16; ++it) {
            int idx = it * 256 + tid; int ci = idx >> 6, f = idx & 63;
            tile[ci][f] = conv_w[(size_t)(t4 * 768 + j * 256 + c0 + ci) * 64 + f];
        }
        __syncthreads();
        #pragma unroll
        for (int it = 0; it < 16; ++it) {
            int idx = it * 256 + tid; int f = idx >> 6, ci = idx & 63;
            W2T[(size_t)((t4 * 3 + j) * 64 + f) * 256 + c0 + ci] = f2bf(tile[ci][f]);
        }
    } else if (id < 96) {
        // WVH = bf16(Wv) row-major [768][256]
        int b2 = id - 48;
        int base = b2 * 4096 + tid * 16;
        #pragma unroll
        for (int q = 0; q < 4; ++q) {
            float4 v = *(const float4*)(Wv + base + q * 4);
            s16x4 h = { f2bf(v.x), f2bf(v.y), f2bf(v.z), f2bf(v.w) };
            *(s16x4*)(WVH + base + q * 4) = h;
        }
    } else if (id < 420) {
        // AB[n][k]: n<128 -> a1 col n ; n>=128 -> v1 col n-128  (both 5184x128)
        int q = id - 96; int kt = q % 81, nt = q / 81;
        const float* src = (nt < 2) ? a1 : v1;
        int col0 = (nt & 1) * 64;
        #pragma unroll
        for (int it = 0; it < 16; ++it) {
            int idx = it * 256 + tid; int ki = idx >> 6, ni = idx & 63;
            tile[ki][ni] = src[(size_t)(kt * 64 + ki) * 128 + col0 + ni];
        }
        __syncthreads();
        #pragma unroll
        for (int it = 0; it < 16; ++it) {
            int idx = it * 256 + tid; int ni = idx >> 6, ki = idx & 63;
            AB[(size_t)(nt * 64 + ni) * 5184 + kt * 64 + ki] = f2bf(tile[ki][ni]);
        }
    } else if (id < 495) {
        // PH[o][d] = bf16( sum_e sprite[o][e]*Wk[d][e] ), o<25
        int g = (id - 420) * 256 + tid;
        int o = g / 768, d = g - o * 768;
        const float* sp = sprite + o * 256;
        const float* wr = Wk + (size_t)d * 256;
        float s = 0.f;
        for (int c = 0; c < 256; ++c) s += sp[c] * wr[c];
        PH[(size_t)o * 768 + d] = f2bf(s);
    } else if (id < 573) {
        // RD[o][n]: o<25 rowdot rows (sprite), o==25 -> bv@W2
        int g = (id - 495) * 256 + tid;
        int o = g / 768, n = g - o * 768;
        int tap = n >> 6, f = n & 63; int t4 = tap / 3, j = tap - t4 * 3;
        const float* sp = (o < 25) ? (sprite + o * 256) : bv;
        float s = 0.f;
        for (int e = 0; e < 256; ++e)
            s += sp[e] * conv_w[(size_t)(t4 * 768 + j * 256 + e) * 64 + f];
        RD[g] = s;
    } else {
        if (tid < 25) {
            float s = 0.f;
            for (int c = 0; c < 256; ++c) s += sprite[tid * 256 + c];
            FL[tid] = (s != 0.0f) ? 1 : 0;
        }
    }
}

// ======== kB2: softmax over 36 scores + weighted sums (pass 2, L3-served) ====
__global__ __launch_bounds__(384) void kB2_sum(
    const float* __restrict__ temb, const float* __restrict__ SK,
    const float* __restrict__ SV, short* __restrict__ XKH, short* __restrict__ XVH)
{
    __shared__ float swk[40], swv[40];
    int tid = threadIdx.x, bs = blockIdx.x;
    int wid = tid >> 6, lane = tid & 63;

    if (wid < 2) {
        const float* S = wid ? SV : SK;
        float s = (lane < 36) ? S[(size_t)bs * 36 + lane] : -INFINITY;
        float m = s;
        #pragma unroll
        for (int off = 32; off; off >>= 1) m = fmaxf(m, __shfl_xor(m, off));
        float e = (lane < 36) ? expf(s - m) : 0.f;
        float z = e;
        #pragma unroll
        for (int off = 32; off; off >>= 1) z += __shfl_xor(z, off);
        float* dst = wid ? swv : swk;
        if (lane < 36) dst[lane] = e / z;
    }
    __syncthreads();

    // thread owns d-columns {2*tid, 2*tid+1}; loop all 36 tokens (coalesced)
    const float2* row = (const float2*)(temb + (size_t)bs * 27648);
    float k0 = 0.f, k1 = 0.f, v0 = 0.f, v1 = 0.f;
    #pragma unroll
    for (int t = 0; t < 36; ++t) {
        float2 x = row[(size_t)t * 384 + tid];
        float wk = swk[t], wv = swv[t];
        k0 += wk * x.x; k1 += wk * x.y;
        v0 += wv * x.x; v1 += wv * x.y;
    }
    ushort2 hk = { (unsigned short)f2bf(k0), (unsigned short)f2bf(k1) };
    ushort2 hv = { (unsigned short)f2bf(v0), (unsigned short)f2bf(v1) };
    *(ushort2*)&XKH[(size_t)bs * 768 + 2 * tid] = hk;
    *(ushort2*)&XVH[(size_t)bs * 768 + 2 * tid] = hv;
}

// ---------------- generic MFMA bf16 GEMM: A[M][K] rm, B[N][K] K-major --------
template<int BIAS, int OUTBF>
__global__ __launch_bounds__(256) void gemm_mfma(
    const short* __restrict__ A, const short* __restrict__ B,
    const float* __restrict__ bias, void* __restrict__ Cout,
    int K, int ldc, int klen, size_t czstride)
{
    __shared__ short As[64][40];
    __shared__ short Bs[64][40];
    int tid = threadIdx.x;
    int bm = blockIdx.x * 64, bn = blockIdx.y * 64;
    int wid = tid >> 6, lane = tid & 63;
    int wm = (wid >> 1) * 32, wn = (wid & 1) * 32;
    int l15 = lane & 15, lg = lane >> 4;

    f32x4 zero = {0.f, 0.f, 0.f, 0.f};
    f32x4 acc00 = zero, acc01 = zero, acc10 = zero, acc11 = zero;

    int srow = tid >> 2, kch = (tid & 3) * 8;
    const short* Ap = A + (size_t)(bm + srow) * K + kch + (size_t)blockIdx.z * klen;
    const short* Bp = B + (size_t)(bn + srow) * K + kch + (size_t)blockIdx.z * klen;

    for (int kt = 0; kt < klen; kt += 32) {
        bf16x8 aval = *(const bf16x8*)(Ap + kt);
        bf16x8 bval = *(const bf16x8*)(Bp + kt);
        *(bf16x8*)&As[srow][kch] = aval;
        *(bf16x8*)&Bs[srow][kch] = bval;
        __syncthreads();
        bf16x8 af0 = *(const bf16x8*)&As[wm + l15][lg * 8];
        bf16x8 af1 = *(const bf16x8*)&As[wm + 16 + l15][lg * 8];
        bf16x8 bg0 = *(const bf16x8*)&Bs[wn + l15][lg * 8];
        bf16x8 bg1 = *(const bf16x8*)&Bs[wn + 16 + l15][lg * 8];
        acc00 = __builtin_amdgcn_mfma_f32_16x16x32_bf16(af0, bg0, acc00, 0, 0, 0);
        acc01 = __builtin_amdgcn_mfma_f32_16x16x32_bf16(af0, bg1, acc01, 0, 0, 0);
        acc10 = __builtin_amdgcn_mfma_f32_16x16x32_bf16(af1, bg0, acc10, 0, 0, 0);
        acc11 = __builtin_amdgcn_mfma_f32_16x16x32_bf16(af1, bg1, acc11, 0, 0, 0);
        __syncthreads();
    }

    float* Cf = (float*)Cout + (size_t)blockIdx.z * czstride;
    short* Ch = (short*)Cout;
    #pragma unroll
    for (int i = 0; i < 2; ++i) {
        f32x4 arow0 = (i == 0) ? acc00 : acc10;
        f32x4 arow1 = (i == 0) ? acc01 : acc11;
        #pragma unroll
        for (int j = 0; j < 2; ++j) {
            f32x4 a = (j == 0) ? arow0 : arow1;
            int col = bn + wn + j * 16 + l15;
            float bb = BIAS ? bias[col] : 0.f;
            #pragma unroll
            for (int r = 0; r < 4; ++r) {
                int row = bm + wm + i * 16 + lg * 4 + r;
                float v = a[r] + bb;
                if (OUTBF) Ch[(size_t)row * ldc + col] = f2bf(v);
                else       Cf[(size_t)row * ldc + col] = v;
            }
        }
    }
}

// ======== k3: fused VW gemm (by<12) + DT gemm (by==12), K=768 ================
__global__ __launch_bounds__(256) void k3_vwdt(
    const short* __restrict__ XVH, const short* __restrict__ WCT,
    const float* __restrict__ bvW2, short* __restrict__ VWH,
    const short* __restrict__ XKH, const short* __restrict__ PH,
    float* __restrict__ DT)
{
    __shared__ short As[64][40];
    __shared__ short Bs[64][40];
    int tid = threadIdx.x;
    bool isdt = (blockIdx.y == 12);
    const short* A = isdt ? XKH : XVH;
    const short* B = isdt ? PH  : WCT;
    int bm = blockIdx.x * 64, bn = isdt ? 0 : blockIdx.y * 64;
    int wid = tid >> 6, lane = tid & 63;
    int wm = (wid >> 1) * 32, wn = (wid & 1) * 32;
    int l15 = lane & 15, lg = lane >> 4;

    f32x4 zero = {0.f, 0.f, 0.f, 0.f};
    f32x4 acc00 = zero, acc01 = zero, acc10 = zero, acc11 = zero;

    int srow = tid >> 2, kch = (tid & 3) * 8;
    const short* Ap = A + (size_t)(bm + srow) * 768 + kch;
    const short* Bp = B + (size_t)(bn + srow) * 768 + kch;

    for (int kt = 0; kt < 768; kt += 32) {
        bf16x8 aval = *(const bf16x8*)(Ap + kt);
        bf16x8 bval = *(const bf16x8*)(Bp + kt);
        *(bf16x8*)&As[srow][kch] = aval;
        *(bf16x8*)&Bs[srow][kch] = bval;
        __syncthreads();
        bf16x8 af0 = *(const bf16x8*)&As[wm + l15][lg * 8];
        bf16x8 af1 = *(const bf16x8*)&As[wm + 16 + l15][lg * 8];
        bf16x8 bg0 = *(const bf16x8*)&Bs[wn + l15][lg * 8];
        bf16x8 bg1 = *(const bf16x8*)&Bs[wn + 16 + l15][lg * 8];
        acc00 = __builtin_amdgcn_mfma_f32_16x16x32_bf16(af0, bg0, acc00, 0, 0, 0);
        acc01 = __builtin_amdgcn_mfma_f32_16x16x32_bf16(af0, bg1, acc01, 0, 0, 0);
        acc10 = __builtin_amdgcn_mfma_f32_16x16x32_bf16(af1, bg0, acc10, 0, 0, 0);
        acc11 = __builtin_amdgcn_mfma_f32_16x16x32_bf16(af1, bg1, acc11, 0, 0, 0);
        __syncthreads();
    }

    #pragma unroll
    for (int i = 0; i < 2; ++i) {
        f32x4 arow0 = (i == 0) ? acc00 : acc10;
        f32x4 arow1 = (i == 0) ? acc01 : acc11;
        #pragma unroll
        for (int j = 0; j < 2; ++j) {
            f32x4 a = (j == 0) ? arow0 : arow1;
            int col = bn + wn + j * 16 + l15;
            #pragma unroll
            for (int r = 0; r < 4; ++r) {
                int row = bm + wm + i * 16 + lg * 4 + r;
                if (isdt) DT[(size_t)row * 64 + col] = a[r];
                else      VWH[(size_t)row * 768 + col] = f2bf(a[r] + bvW2[col]);
            }
        }
    }
}

// ======== k4: wts + factored conv + transpose-flatten + lrelu ================
__global__ __launch_bounds__(512) void k4_y(
    const int* __restrict__ state, const float* __restrict__ dt,
    const int* __restrict__ flags, const short* __restrict__ VWH,
    const float* __restrict__ rowdot, const float* __restrict__ conv_b,
    short* __restrict__ y)
{
    int b = blockIdx.x, tid = threadIdx.x;
    __shared__ float s_vW[3 * 768];
    __shared__ float s_w[3][NPOS + 4];
    __shared__ int   s_avt[NPOS + 4];
    __shared__ float s_y[81 * 65];

    const unsigned* vr = (const unsigned*)(VWH + (size_t)b * 3 * 768);
    for (int i = tid; i < 1152; i += 512) {
        unsigned u = vr[i];
        s_vW[2 * i]     = bf2f_lo(u);
        s_vW[2 * i + 1] = bf2f_hi(u);
    }

    for (int code = tid; code < NPOS; code += 512) {
        const int* st = state + ((size_t)b * NPOS + code) * 4;
        int o0 = st[0], o1 = st[1], o2 = st[2], avi = st[3];
        int cnt = flags[o0] + flags[o1] + flags[o2];
        s_avt[code] = avi;
        float w0 = 0.f, w1 = 0.f, w2 = 0.f;
        if (cnt > 0) {
            const float* d0 = dt + (size_t)b * 192;   // [3][64]
            float inv = 1.0f / (16.0f * (float)cnt);
            float q0 = (d0[o0]       + d0[o1]       + d0[o2])       * inv;
            float q1 = (d0[64 + o0]  + d0[64 + o1]  + d0[64 + o2])  * inv;
            float q2 = (d0[128 + o0] + d0[128 + o1] + d0[128 + o2]) * inv;
            float m = fmaxf(q0, fmaxf(q1, q2));
            float e0 = expf(q0 - m), e1 = expf(q1 - m), e2 = expf(q2 - m);
            float is = 1.0f / (6.0f * (e0 + e1 + e2));   // folds att/3 and st/2
            w0 = e0 * is; w1 = e1 * is; w2 = e2 * is;
        }
        s_w[0][code] = w0; s_w[1][code] = w1; s_w[2][code] = w2;
    }
    __syncthreads();

    int f = tid & 63;
    float cb = conv_b[f];
    for (int p = tid >> 6; p < 81; p += 8) {
        int oh = p / 9, ow = p - oh * 9;
        float acc = cb;
        #pragma unroll
        for (int kh = 0; kh < 2; ++kh)
        #pragma unroll
        for (int kw = 0; kw < 2; ++kw) {
            int bc = 3 * ((oh + kh) * 10 + (ow + kw));
            int tbase = ((kh * 2 + kw) * 3) * 64 + f;
            #pragma unroll
            for (int j = 0; j < 3; ++j) {
                int code = bc + j;
                int tf = tbase + j * 64;
                acc += s_w[0][code] * s_vW[tf]
                     + s_w[1][code] * s_vW[768 + tf]
                     + s_w[2][code] * s_vW[2 * 768 + tf];
                acc += 0.5f * rowdot[(size_t)s_avt[code] * 768 + tf];
            }
        }
        acc = acc > 0.f ? acc : 0.01f * acc;
        s_y[p * 65 + f] = acc;
    }
    __syncthreads();
    for (int i = tid; i < LIN; i += 512) {
        int ff = i / 81, pp = i - ff * 81;
        y[(size_t)b * LIN + i] = f2bf(s_y[pp * 65 + ff]);
    }
}

// ======== k6: split-K reduce + layer2 + heads ================================
__global__ __launch_bounds__(128) void k6_heads(
    const float* __restrict__ PART, const float* __restrict__ a1b,
    const float* __restrict__ v1b, const int* __restrict__ action,
    const float* __restrict__ a2, const float* __restrict__ a2b,
    const float* __restrict__ a3, const float* __restrict__ a3b,
    const float* __restrict__ v2, const float* __restrict__ v2b,
    const float* __restrict__ v3, const float* __restrict__ v3b,
    float* __restrict__ out)
{
    int b = blockIdx.x, tid = threadIdx.x;
    __shared__ float h1a[128], h1v[128], h2a[128], red[128];
    __shared__ float lg[5];
    float sa0 = a1b[tid], sv0 = v1b[tid];
    const float* pb = PART + (size_t)b * 256;
    for (int z = 0; z < KSPLIT; ++z) {
        sa0 += pb[(size_t)z * (BS * 256) + tid];
        sv0 += pb[(size_t)z * (BS * 256) + 128 + tid];
    }
    h1a[tid] = sa0 > 0.f ? sa0 : 0.01f * sa0;
    h1v[tid] = sv0 > 0.f ? sv0 : 0.01f * sv0;
    __syncthreads();
    float sa = a2b[tid], sv = v2b[tid];
    for (int k = 0; k < 128; ++k) {
        sa += h1a[k] * a2[k * 128 + tid];
        sv += h1v[k] * v2[k * 128 + tid];
    }
    sa = sa > 0.f ? sa : 0.01f * sa;
    sv = sv > 0.f ? sv : 0.01f * sv;
    h2a[tid] = sa;
    red[tid] = sv * v3[tid];
    __syncthreads();
    for (int s = 64; s > 0; s >>= 1) {
        if (tid < s) red[tid] += red[tid + s];
        __syncthreads();
    }
    if (tid < 5) {
        float l = a3b[tid];
        for (int k = 0; k < 128; ++k) l += h2a[k] * a3[k * 5 + tid];
        lg[tid] = l;
    }
    __syncthreads();
    if (tid == 0) {
        float m = lg[0];
        for (int j2 = 1; j2 < 5; ++j2) m = fmaxf(m, lg[j2]);
        float se = 0.f;
        for (int j2 = 0; j2 < 5; ++j2) se += expf(lg[j2] - m);
        float lse = m + logf(se);
        int act = action[b];
        float ent = 0.f;
        for (int j2 = 0; j2 < 5; ++j2) {
            float lp = lg[j2] - lse;
            ent -= expf(lp) * lp;
        }
        out[b]        = lg[act] - lse;
        out[512 + b]  = red[0] + v3b[0];
        out[1024 + b] = ent;
    }
}

// ---------------- launch ----------------
extern "C" void kernel_launch(void* const* d_in, const int* in_sizes, int n_in,
                              void* d_out, int out_size, void* d_ws, size_t ws_size,
                              hipStream_t stream)
{
    const int*   state  = (const int*)d_in[0];
    const int*   action = (const int*)d_in[1];
    const float* temb   = (const float*)d_in[2];
    const float* sprite = (const float*)d_in[3];
    const float* conv_w = (const float*)d_in[4];
    const float* conv_b = (const float*)d_in[5];
    const float* Wk     = (const float*)d_in[6];
    const float* Wks    = (const float*)d_in[8];
    const float* Wv     = (const float*)d_in[10];
    const float* bv     = (const float*)d_in[11];
    const float* Wvs    = (const float*)d_in[12];
    const float* a1     = (const float*)d_in[14];
    const float* a1b    = (const float*)d_in[15];
    const float* a2     = (const float*)d_in[16];
    const float* a2b    = (const float*)d_in[17];
    const float* a3     = (const float*)d_in[18];
    const float* a3b    = (const float*)d_in[19];
    const float* v1     = (const float*)d_in[20];
    const float* v1b    = (const float*)d_in[21];
    const float* v2     = (const float*)d_in[22];
    const float* v2b    = (const float*)d_in[23];
    const float* v3     = (const float*)d_in[24];
    const float* v3b    = (const float*)d_in[25];
    (void)in_sizes; (void)n_in; (void)out_size; (void)ws_size;

    float* ws  = (float*)d_ws;
    float* RD  = ws + OFF_RD;
    float* bvW2= RD + 25 * 768;
    int*   FL  = (int*)(ws + OFF_FL);
    float* DT  = ws + OFF_DT;
    short* W2T = (short*)(ws + OFF_W2T);
    short* WVH = (short*)(ws + OFF_WVH);
    short* WCT = (short*)(ws + OFF_WCT);
    short* PH  = (short*)(ws + OFF_PH);
    short* AB  = (short*)(ws + OFF_AB);
    float* SK  = ws + OFF_SK;
    float* SV  = ws + OFF_SV;
    short* XKH = (short*)(ws + OFF_XKH);
    short* XVH = (short*)(ws + OFF_XVH);
    short* VWH = (short*)(ws + OFF_VWH);
    short* YH  = (short*)(ws + OFF_YH);
    float* PART= ws + OFF_PART;
    float* out = (float*)d_out;

    // 1) pass-1 scores (streams temb once) + all prep
    k1_scores_prep<<<13824 + 574, 256, 0, stream>>>(
        temb, Wks, Wvs, conv_w, sprite, Wk, Wv, bv, a1, v1,
        SK, SV, W2T, WVH, AB, PH, RD, FL);
    // 2) pass-2 softmax + weighted sums (temb from L3)
    kB2_sum<<<NBS, 384, 0, stream>>>(temb, SK, SV, XKH, XVH);
    // 3) WCT[tf][d] = sum_c W2[tf][c]*Wv[d][c]   (768x768, K=256) -> bf16
    gemm_mfma<0,1><<<dim3(12,12,1),256,0,stream>>>(W2T, WVH, nullptr, WCT, 256, 768, 256, 0);
    // 4) VWH = XVH@WCT^T + bv@W2 (bf16)  ||  DT = XKH@PH^T (fp32)
    k3_vwdt<<<dim3(24,13,1),256,0,stream>>>(XVH, WCT, bvW2, VWH, XKH, PH, DT);
    // 5) conv + flatten
    k4_y<<<BS, 512, 0, stream>>>(state, DT, FL, VWH, RD, conv_b, YH);
    // 6) layer-1 split-K GEMM
    gemm_mfma<0,0><<<dim3(8,4,KSPLIT),256,0,stream>>>(YH, AB, nullptr, PART, 5184, 256, KCH, (size_t)BS*256);
    // 7) reduce + heads
    k6_heads<<<BS, 128, 0, stream>>>(PART, a1b, v1b, action, a2, a2b, a3, a3b,
                                     v2, v2b, v3, v3b, out);
}

// Round 6
// 128.747 us; speedup vs baseline: 1.2396x; 1.0173x over previous
//
#include <hip/hip_runtime.h>
#include <hip/hip_bf16.h>
#include <math.h>

// ---------------- problem constants ----------------
constexpr int BS   = 512;
constexpr int NBS  = 1536;   // BS * NSENT
constexpr int NPOS = 300;    // HIST*H*W
constexpr int LIN  = 5184;   // FM * 9 * 9
constexpr int KSPLIT = 9, KCH = 576;    // 9*576 = 5184

typedef __attribute__((ext_vector_type(8))) short bf16x8;
typedef __attribute__((ext_vector_type(4))) float f32x4;

static __device__ __forceinline__ short f2bf(float f) {
    unsigned u = __float_as_uint(f);
    unsigned r = (u + 0x7FFFu + ((u >> 16) & 1u)) >> 16;
    return (short)r;
}
static __device__ __forceinline__ unsigned pk2(float a, float b) {
    return ((unsigned)(unsigned short)f2bf(a)) | (((unsigned)(unsigned short)f2bf(b)) << 16);
}
static __device__ __forceinline__ float bf2f_lo(unsigned u) { return __uint_as_float(u << 16); }
static __device__ __forceinline__ float bf2f_hi(unsigned u) { return __uint_as_float(u & 0xFFFF0000u); }

// ---------------- workspace layout (float offsets) ----------------
constexpr size_t OFF_RD   = 0;         // 26*768 fp32 (0..24 rowdot, 25 = bv@W2)
constexpr size_t OFF_FL   = 19968;     // 64 (int)
constexpr size_t OFF_DT   = 20032;     // fp32 [1536][64]
constexpr size_t OFF_WCT  = 118336;    // bf16 [768][768] -> 294912 floats
constexpr size_t OFF_PH   = 413248;    // bf16 [64][768]  -> 24576
constexpr size_t OFF_AB   = 437824;    // bf16 [256][5184] -> 663552
constexpr size_t OFF_XKH  = 1101376;   // bf16 [1536][768] -> 589824
constexpr size_t OFF_XVH  = 1691200;   // bf16 [1536][768] -> 589824
constexpr size_t OFF_VWH  = 2281024;   // bf16 [1536][768] -> 589824
constexpr size_t OFF_YH   = 2870848;   // bf16 [512][5184] -> 1327104
constexpr size_t OFF_PART = 4197952;   // fp32 [9][512][256]; end 5377600 (~21.5MB)

// ======== k1: single-pass temb (bf16 LDS staging) + all prep =================
// blocks 0..1535 : per-(b,s): stage row as bf16 in LDS (read temb ONCE),
//                  scores -> softmax -> weighted sums -> XKH/XVH (bf16)
// blocks 1536+   : prep (AB repack, PH, RD+bvW2, WCT fp32 gemm, flags)
__global__ __launch_bounds__(512) void k1_fused(
    const float* __restrict__ temb, const float* __restrict__ Wks,
    const float* __restrict__ Wvs, const float* __restrict__ conv_w,
    const float* __restrict__ sprite, const float* __restrict__ Wk,
    const float* __restrict__ Wv, const float* __restrict__ bv,
    const float* __restrict__ a1, const float* __restrict__ v1,
    short* __restrict__ XKH, short* __restrict__ XVH,
    short* __restrict__ AB, short* __restrict__ PH, short* __restrict__ WCT,
    float* __restrict__ RD, int* __restrict__ FL)
{
    __shared__ unsigned smem[13824 + 160];   // 55.9 KB -> 2 blocks/CU
    unsigned* hbuf = smem;                   // [36*384] bf16x2 row buffer
    float (*sco)[40] = (float(*)[40])(smem + 13824);
    int tid = threadIdx.x, bx = blockIdx.x;
    int lane = tid & 63, w = tid >> 6;

    if (bx < NBS) {
        int bs = bx;
        const float4* src4 = (const float4*)temb + (size_t)bs * 6912;

        // ---- half 0 (tokens 0..17, float4 idx 0..3455): load->pack->LDS ----
        #pragma unroll
        for (int c = 0; c < 7; ++c) {
            int i = c * 512 + tid;
            if (c < 6 || tid < 384) {
                float4 v = src4[i];
                hbuf[2 * i]     = pk2(v.x, v.y);
                hbuf[2 * i + 1] = pk2(v.z, v.w);
            }
        }
        __syncthreads();

        // ---- half 1: issue loads EARLY into named regs (no arrays!) ----
        float4 q0, q1, q2, q3, q4, q5, q6 = make_float4(0.f, 0.f, 0.f, 0.f);
        q0 = src4[3456 + tid];
        q1 = src4[3968 + tid];
        q2 = src4[4480 + tid];
        q3 = src4[4992 + tid];
        q4 = src4[5504 + tid];
        q5 = src4[6016 + tid];
        if (tid < 384) q6 = src4[6528 + tid];

        // ---- scores for half-0 tokens (overlaps half-1 HBM latency) ----
        const float2* wks2 = (const float2*)Wks;
        const float2* wvs2 = (const float2*)Wvs;
        #pragma unroll
        for (int rr = 0; rr < 3; ++rr) {
            int t = w + 8 * rr;
            if (rr < 2 || w < 2) {
                float pk = 0.f, pv = 0.f;
                #pragma unroll
                for (int j = 0; j < 6; ++j) {
                    unsigned u = hbuf[t * 384 + lane + 64 * j];
                    float x0 = bf2f_lo(u), x1 = bf2f_hi(u);
                    float2 a = wks2[lane + 64 * j];
                    float2 b = wvs2[lane + 64 * j];
                    pk += x0 * a.x + x1 * a.y;
                    pv += x0 * b.x + x1 * b.y;
                }
                #pragma unroll
                for (int off = 32; off; off >>= 1) {
                    pk += __shfl_down(pk, off);
                    pv += __shfl_down(pv, off);
                }
                if (lane == 0) { sco[0][t] = pk; sco[1][t] = pv; }
            }
        }

        // ---- write half 1 to LDS (disjoint region; no barrier needed first) ----
        hbuf[2 * (3456 + tid)]     = pk2(q0.x, q0.y);
        hbuf[2 * (3456 + tid) + 1] = pk2(q0.z, q0.w);
        hbuf[2 * (3968 + tid)]     = pk2(q1.x, q1.y);
        hbuf[2 * (3968 + tid) + 1] = pk2(q1.z, q1.w);
        hbuf[2 * (4480 + tid)]     = pk2(q2.x, q2.y);
        hbuf[2 * (4480 + tid) + 1] = pk2(q2.z, q2.w);
        hbuf[2 * (4992 + tid)]     = pk2(q3.x, q3.y);
        hbuf[2 * (4992 + tid) + 1] = pk2(q3.z, q3.w);
        hbuf[2 * (5504 + tid)]     = pk2(q4.x, q4.y);
        hbuf[2 * (5504 + tid) + 1] = pk2(q4.z, q4.w);
        hbuf[2 * (6016 + tid)]     = pk2(q5.x, q5.y);
        hbuf[2 * (6016 + tid) + 1] = pk2(q5.z, q5.w);
        if (tid < 384) {
            hbuf[2 * (6528 + tid)]     = pk2(q6.x, q6.y);
            hbuf[2 * (6528 + tid) + 1] = pk2(q6.z, q6.w);
        }
        __syncthreads();

        // ---- scores for half-1 tokens (18..35) ----
        #pragma unroll
        for (int rr = 0; rr < 3; ++rr) {
            int t = 18 + w + 8 * rr;
            if (rr < 2 || w < 2) {
                float pk = 0.f, pv = 0.f;
                #pragma unroll
                for (int j = 0; j < 6; ++j) {
                    unsigned u = hbuf[t * 384 + lane + 64 * j];
                    float x0 = bf2f_lo(u), x1 = bf2f_hi(u);
                    float2 a = wks2[lane + 64 * j];
                    float2 b = wvs2[lane + 64 * j];
                    pk += x0 * a.x + x1 * a.y;
                    pv += x0 * b.x + x1 * b.y;
                }
                #pragma unroll
                for (int off = 32; off; off >>= 1) {
                    pk += __shfl_down(pk, off);
                    pv += __shfl_down(pv, off);
                }
                if (lane == 0) { sco[0][t] = pk; sco[1][t] = pv; }
            }
        }
        __syncthreads();

        // ---- exact softmax over 36 (waves 0,1 handle k,v) ----
        if (w < 2) {
            float s = (lane < 36) ? sco[w][lane] : -INFINITY;
            float m = s;
            #pragma unroll
            for (int off = 32; off; off >>= 1) m = fmaxf(m, __shfl_xor(m, off));
            float e = (lane < 36) ? expf(s - m) : 0.f;
            float z = e;
            #pragma unroll
            for (int off = 32; off; off >>= 1) z += __shfl_xor(z, off);
            if (lane < 36) sco[2 + w][lane] = e / z;
        }
        __syncthreads();

        // ---- weighted sums from LDS: thread owns dims {2tid, 2tid+1} ----
        if (tid < 384) {
            float k0 = 0.f, k1 = 0.f, v0 = 0.f, v1 = 0.f;
            #pragma unroll
            for (int t = 0; t < 36; ++t) {
                unsigned u = hbuf[t * 384 + tid];
                float x0 = bf2f_lo(u), x1 = bf2f_hi(u);
                float wk = sco[2][t], wv = sco[3][t];
                k0 += wk * x0; k1 += wk * x1;
                v0 += wv * x0; v1 += wv * x1;
            }
            ((unsigned*)XKH)[(size_t)bs * 384 + tid] = pk2(k0, k1);
            ((unsigned*)XVH)[(size_t)bs * 384 + tid] = pk2(v0, v1);
        }
        return;
    }

    // ================= prep blocks =================
    int id = bx - NBS;
    if (id < 324) {
        // AB[n][k]: n<128 -> a1 col n ; n>=128 -> v1 col n-128  (both 5184x128)
        float (*tile)[65] = (float(*)[65])smem;
        int kt = id % 81, nt = id / 81;
        const float* src = (nt < 2) ? a1 : v1;
        int col0 = (nt & 1) * 64;
        #pragma unroll
        for (int it = 0; it < 8; ++it) {
            int idx = it * 512 + tid; int ki = idx >> 6, ni = idx & 63;
            tile[ki][ni] = src[(size_t)(kt * 64 + ki) * 128 + col0 + ni];
        }
        __syncthreads();
        #pragma unroll
        for (int it = 0; it < 8; ++it) {
            int idx = it * 512 + tid; int ni = idx >> 6, ki = idx & 63;
            AB[(size_t)(nt * 64 + ni) * 5184 + kt * 64 + ki] = f2bf(tile[ki][ni]);
        }
    } else if (id < 362) {
        // PH[o][d] = bf16( sum_c sprite[o][c]*Wk[d][c] ), o<25
        int g = (id - 324) * 512 + tid;
        if (g < 19200) {
            int o = g / 768, d = g - o * 768;
            const float* sp = sprite + o * 256;
            const float* wr = Wk + (size_t)d * 256;
            float s = 0.f;
            for (int c = 0; c < 256; ++c) s += sp[c] * wr[c];
            PH[(size_t)o * 768 + d] = f2bf(s);
        }
    } else if (id < 401) {
        // RD[o][n]: o<25 rowdot rows (sprite), o==25 -> bv@W2
        int g = (id - 362) * 512 + tid;
        if (g < 19968) {
            int o = g / 768, n = g - o * 768;
            int tap = n >> 6, f = n & 63; int t4 = tap / 3, j = tap - t4 * 3;
            const float* sp = (o < 25) ? (sprite + o * 256) : bv;
            float s = 0.f;
            for (int e = 0; e < 256; ++e)
                s += sp[e] * conv_w[(size_t)(t4 * 768 + j * 256 + e) * 64 + f];
            RD[g] = s;
        }
    } else if (id < 545) {
        // WCT[tf][d] = sum_c W2[tf][c]*Wv[d][c] in fp32, store bf16
        // W2[tf][c] = conv_w[(t4*768+jj*256+c)*64 + f], tf=(t4*3+jj)*64+f
        int wid2 = id - 401;
        int bm = (wid2 / 12) * 64, bn = (wid2 % 12) * 64;
        int p = bm >> 6; int t4 = p / 3, jj = p - t4 * 3;
        const float* cwb = conv_w + (size_t)(t4 * 768 + jj * 256) * 64;
        float* As = (float*)smem;            // [64][65]
        float* Bs = (float*)smem + 4160;     // [64][65]
        float acc[4][4];
        #pragma unroll
        for (int i = 0; i < 4; ++i)
            #pragma unroll
            for (int j = 0; j < 4; ++j) acc[i][j] = 0.f;
        int tm = (tid & 255) >> 4, tn = tid & 15;
        for (int kc = 0; kc < 256; kc += 64) {
            #pragma unroll
            for (int it = 0; it < 8; ++it) {
                int idx = it * 512 + tid; int c = idx >> 6, f = idx & 63;
                As[c * 65 + f] = cwb[(size_t)(kc + c) * 64 + f];
            }
            #pragma unroll
            for (int it = 0; it < 8; ++it) {
                int idx = it * 512 + tid; int d = idx >> 6, c = idx & 63;
                Bs[c * 65 + d] = Wv[(size_t)(bn + d) * 256 + kc + c];
            }
            __syncthreads();
            if (tid < 256) {
                for (int kk = 0; kk < 64; ++kk) {
                    float a[4], b[4];
                    #pragma unroll
                    for (int i = 0; i < 4; ++i) a[i] = As[kk * 65 + tm * 4 + i];
                    #pragma unroll
                    for (int j = 0; j < 4; ++j) b[j] = Bs[kk * 65 + tn * 4 + j];
                    #pragma unroll
                    for (int i = 0; i < 4; ++i)
                        #pragma unroll
                        for (int j = 0; j < 4; ++j) acc[i][j] += a[i] * b[j];
                }
            }
            __syncthreads();
        }
        if (tid < 256) {
            #pragma unroll
            for (int i = 0; i < 4; ++i)
                #pragma unroll
                for (int j = 0; j < 4; ++j)
                    WCT[(size_t)(bm + tm * 4 + i) * 768 + bn + tn * 4 + j] = f2bf(acc[i][j]);
        }
    } else {
        if (tid < 25) {
            float s = 0.f;
            for (int c = 0; c < 256; ++c) s += sprite[tid * 256 + c];
            FL[tid] = (s != 0.0f) ? 1 : 0;
        }
    }
}

// ---------------- generic MFMA bf16 GEMM: A[M][K] rm, B[N][K] K-major --------
template<int BIAS, int OUTBF>
__global__ __launch_bounds__(256) void gemm_mfma(
    const short* __restrict__ A, const short* __restrict__ B,
    const float* __restrict__ bias, void* __restrict__ Cout,
    int K, int ldc, int klen, size_t czstride)
{
    __shared__ short As[64][40];
    __shared__ short Bs[64][40];
    int tid = threadIdx.x;
    int bm = blockIdx.x * 64, bn = blockIdx.y * 64;
    int wid = tid >> 6, lane = tid & 63;
    int wm = (wid >> 1) * 32, wn = (wid & 1) * 32;
    int l15 = lane & 15, lg = lane >> 4;

    f32x4 zero = {0.f, 0.f, 0.f, 0.f};
    f32x4 acc00 = zero, acc01 = zero, acc10 = zero, acc11 = zero;

    int srow = tid >> 2, kch = (tid & 3) * 8;
    const short* Ap = A + (size_t)(bm + srow) * K + kch + (size_t)blockIdx.z * klen;
    const short* Bp = B + (size_t)(bn + srow) * K + kch + (size_t)blockIdx.z * klen;

    for (int kt = 0; kt < klen; kt += 32) {
        bf16x8 aval = *(const bf16x8*)(Ap + kt);
        bf16x8 bval = *(const bf16x8*)(Bp + kt);
        *(bf16x8*)&As[srow][kch] = aval;
        *(bf16x8*)&Bs[srow][kch] = bval;
        __syncthreads();
        bf16x8 af0 = *(const bf16x8*)&As[wm + l15][lg * 8];
        bf16x8 af1 = *(const bf16x8*)&As[wm + 16 + l15][lg * 8];
        bf16x8 bg0 = *(const bf16x8*)&Bs[wn + l15][lg * 8];
        bf16x8 bg1 = *(const bf16x8*)&Bs[wn + 16 + l15][lg * 8];
        acc00 = __builtin_amdgcn_mfma_f32_16x16x32_bf16(af0, bg0, acc00, 0, 0, 0);
        acc01 = __builtin_amdgcn_mfma_f32_16x16x32_bf16(af0, bg1, acc01, 0, 0, 0);
        acc10 = __builtin_amdgcn_mfma_f32_16x16x32_bf16(af1, bg0, acc10, 0, 0, 0);
        acc11 = __builtin_amdgcn_mfma_f32_16x16x32_bf16(af1, bg1, acc11, 0, 0, 0);
        __syncthreads();
    }

    float* Cf = (float*)Cout + (size_t)blockIdx.z * czstride;
    short* Ch = (short*)Cout;
    #pragma unroll
    for (int i = 0; i < 2; ++i) {
        f32x4 arow0 = (i == 0) ? acc00 : acc10;
        f32x4 arow1 = (i == 0) ? acc01 : acc11;
        #pragma unroll
        for (int j = 0; j < 2; ++j) {
            f32x4 a = (j == 0) ? arow0 : arow1;
            int col = bn + wn + j * 16 + l15;
            float bb = BIAS ? bias[col] : 0.f;
            #pragma unroll
            for (int r = 0; r < 4; ++r) {
                int row = bm + wm + i * 16 + lg * 4 + r;
                float v = a[r] + bb;
                if (OUTBF) Ch[(size_t)row * ldc + col] = f2bf(v);
                else       Cf[(size_t)row * ldc + col] = v;
            }
        }
    }
}

// ======== k3: fused VW gemm (by<12) + DT gemm (by==12), K=768 ================
__global__ __launch_bounds__(256) void k3_vwdt(
    const short* __restrict__ XVH, const short* __restrict__ WCT,
    const float* __restrict__ bvW2, short* __restrict__ VWH,
    const short* __restrict__ XKH, const short* __restrict__ PH,
    float* __restrict__ DT)
{
    __shared__ short As[64][40];
    __shared__ short Bs[64][40];
    int tid = threadIdx.x;
    bool isdt = (blockIdx.y == 12);
    const short* A = isdt ? XKH : XVH;
    const short* B = isdt ? PH  : WCT;
    int bm = blockIdx.x * 64, bn = isdt ? 0 : blockIdx.y * 64;
    int wid = tid >> 6, lane = tid & 63;
    int wm = (wid >> 1) * 32, wn = (wid & 1) * 32;
    int l15 = lane & 15, lg = lane >> 4;

    f32x4 zero = {0.f, 0.f, 0.f, 0.f};
    f32x4 acc00 = zero, acc01 = zero, acc10 = zero, acc11 = zero;

    int srow = tid >> 2, kch = (tid & 3) * 8;
    const short* Ap = A + (size_t)(bm + srow) * 768 + kch;
    const short* Bp = B + (size_t)(bn + srow) * 768 + kch;

    for (int kt = 0; kt < 768; kt += 32) {
        bf16x8 aval = *(const bf16x8*)(Ap + kt);
        bf16x8 bval = *(const bf16x8*)(Bp + kt);
        *(bf16x8*)&As[srow][kch] = aval;
        *(bf16x8*)&Bs[srow][kch] = bval;
        __syncthreads();
        bf16x8 af0 = *(const bf16x8*)&As[wm + l15][lg * 8];
        bf16x8 af1 = *(const bf16x8*)&As[wm + 16 + l15][lg * 8];
        bf16x8 bg0 = *(const bf16x8*)&Bs[wn + l15][lg * 8];
        bf16x8 bg1 = *(const bf16x8*)&Bs[wn + 16 + l15][lg * 8];
        acc00 = __builtin_amdgcn_mfma_f32_16x16x32_bf16(af0, bg0, acc00, 0, 0, 0);
        acc01 = __builtin_amdgcn_mfma_f32_16x16x32_bf16(af0, bg1, acc01, 0, 0, 0);
        acc10 = __builtin_amdgcn_mfma_f32_16x16x32_bf16(af1, bg0, acc10, 0, 0, 0);
        acc11 = __builtin_amdgcn_mfma_f32_16x16x32_bf16(af1, bg1, acc11, 0, 0, 0);
        __syncthreads();
    }

    #pragma unroll
    for (int i = 0; i < 2; ++i) {
        f32x4 arow0 = (i == 0) ? acc00 : acc10;
        f32x4 arow1 = (i == 0) ? acc01 : acc11;
        #pragma unroll
        for (int j = 0; j < 2; ++j) {
            f32x4 a = (j == 0) ? arow0 : arow1;
            int col = bn + wn + j * 16 + l15;
            #pragma unroll
            for (int r = 0; r < 4; ++r) {
                int row = bm + wm + i * 16 + lg * 4 + r;
                if (isdt) DT[(size_t)row * 64 + col] = a[r];
                else      VWH[(size_t)row * 768 + col] = f2bf(a[r] + bvW2[col]);
            }
        }
    }
}

// ======== k4: wts + factored conv + transpose-flatten + lrelu ================
__global__ __launch_bounds__(512) void k4_y(
    const int* __restrict__ state, const float* __restrict__ dt,
    const int* __restrict__ flags, const short* __restrict__ VWH,
    const float* __restrict__ rowdot, const float* __restrict__ conv_b,
    short* __restrict__ y)
{
    int b = blockIdx.x, tid = threadIdx.x;
    __shared__ float s_vW[3 * 768];
    __shared__ float s_w[3][NPOS + 4];
    __shared__ int   s_avt[NPOS + 4];
    __shared__ float s_y[81 * 65];

    const unsigned* vr = (const unsigned*)(VWH + (size_t)b * 3 * 768);
    for (int i = tid; i < 1152; i += 512) {
        unsigned u = vr[i];
        s_vW[2 * i]     = bf2f_lo(u);
        s_vW[2 * i + 1] = bf2f_hi(u);
    }

    for (int code = tid; code < NPOS; code += 512) {
        const int* st = state + ((size_t)b * NPOS + code) * 4;
        int o0 = st[0], o1 = st[1], o2 = st[2], avi = st[3];
        int cnt = flags[o0] + flags[o1] + flags[o2];
        s_avt[code] = avi;
        float w0 = 0.f, w1 = 0.f, w2 = 0.f;
        if (cnt > 0) {
            const float* d0 = dt + (size_t)b * 192;   // [3][64]
            float inv = 1.0f / (16.0f * (float)cnt);
            float q0 = (d0[o0]       + d0[o1]       + d0[o2])       * inv;
            float q1 = (d0[64 + o0]  + d0[64 + o1]  + d0[64 + o2])  * inv;
            float q2 = (d0[128 + o0] + d0[128 + o1] + d0[128 + o2]) * inv;
            float m = fmaxf(q0, fmaxf(q1, q2));
            float e0 = expf(q0 - m), e1 = expf(q1 - m), e2 = expf(q2 - m);
            float is = 1.0f / (6.0f * (e0 + e1 + e2));   // folds att/3 and st/2
            w0 = e0 * is; w1 = e1 * is; w2 = e2 * is;
        }
        s_w[0][code] = w0; s_w[1][code] = w1; s_w[2][code] = w2;
    }
    __syncthreads();

    int f = tid & 63;
    float cb = conv_b[f];
    for (int p = tid >> 6; p < 81; p += 8) {
        int oh = p / 9, ow = p - oh * 9;
        float acc = cb;
        #pragma unroll
        for (int kh = 0; kh < 2; ++kh)
        #pragma unroll
        for (int kw = 0; kw < 2; ++kw) {
            int bc = 3 * ((oh + kh) * 10 + (ow + kw));
            int tbase = ((kh * 2 + kw) * 3) * 64 + f;
            #pragma unroll
            for (int j = 0; j < 3; ++j) {
                int code = bc + j;
                int tf = tbase + j * 64;
                acc += s_w[0][code] * s_vW[tf]
                     + s_w[1][code] * s_vW[768 + tf]
                     + s_w[2][code] * s_vW[2 * 768 + tf];
                acc += 0.5f * rowdot[(size_t)s_avt[code] * 768 + tf];
            }
        }
        acc = acc > 0.f ? acc : 0.01f * acc;
        s_y[p * 65 + f] = acc;
    }
    __syncthreads();
    for (int i = tid; i < LIN; i += 512) {
        int ff = i / 81, pp = i - ff * 81;
        y[(size_t)b * LIN + i] = f2bf(s_y[pp * 65 + ff]);
    }
}

// ======== k6: split-K reduce + layer2 + heads ================================
__global__ __launch_bounds__(128) void k6_heads(
    const float* __restrict__ PART, const float* __restrict__ a1b,
    const float* __restrict__ v1b, const int* __restrict__ action,
    const float* __restrict__ a2, const float* __restrict__ a2b,
    const float* __restrict__ a3, const float* __restrict__ a3b,
    const float* __restrict__ v2, const float* __restrict__ v2b,
    const float* __restrict__ v3, const float* __restrict__ v3b,
    float* __restrict__ out)
{
    int b = blockIdx.x, tid = threadIdx.x;
    __shared__ float h1a[128], h1v[128], h2a[128], red[128];
    __shared__ float lg[5];
    float sa0 = a1b[tid], sv0 = v1b[tid];
    const float* pb = PART + (size_t)b * 256;
    for (int z = 0; z < KSPLIT; ++z) {
        sa0 += pb[(size_t)z * (BS * 256) + tid];
        sv0 += pb[(size_t)z * (BS * 256) + 128 + tid];
    }
    h1a[tid] = sa0 > 0.f ? sa0 : 0.01f * sa0;
    h1v[tid] = sv0 > 0.f ? sv0 : 0.01f * sv0;
    __syncthreads();
    float sa = a2b[tid], sv = v2b[tid];
    for (int k = 0; k < 128; ++k) {
        sa += h1a[k] * a2[k * 128 + tid];
        sv += h1v[k] * v2[k * 128 + tid];
    }
    sa = sa > 0.f ? sa : 0.01f * sa;
    sv = sv > 0.f ? sv : 0.01f * sv;
    h2a[tid] = sa;
    red[tid] = sv * v3[tid];
    __syncthreads();
    for (int s = 64; s > 0; s >>= 1) {
        if (tid < s) red[tid] += red[tid + s];
        __syncthreads();
    }
    if (tid < 5) {
        float l = a3b[tid];
        for (int k = 0; k < 128; ++k) l += h2a[k] * a3[k * 5 + tid];
        lg[tid] = l;
    }
    __syncthreads();
    if (tid == 0) {
        float m = lg[0];
        for (int j2 = 1; j2 < 5; ++j2) m = fmaxf(m, lg[j2]);
        float se = 0.f;
        for (int j2 = 0; j2 < 5; ++j2) se += expf(lg[j2] - m);
        float lse = m + logf(se);
        int act = action[b];
        float ent = 0.f;
        for (int j2 = 0; j2 < 5; ++j2) {
            float lp = lg[j2] - lse;
            ent -= expf(lp) * lp;
        }
        out[b]        = lg[act] - lse;
        out[512 + b]  = red[0] + v3b[0];
        out[1024 + b] = ent;
    }
}

// ---------------- launch ----------------
extern "C" void kernel_launch(void* const* d_in, const int* in_sizes, int n_in,
                              void* d_out, int out_size, void* d_ws, size_t ws_size,
                              hipStream_t stream)
{
    const int*   state  = (const int*)d_in[0];
    const int*   action = (const int*)d_in[1];
    const float* temb   = (const float*)d_in[2];
    const float* sprite = (const float*)d_in[3];
    const float* conv_w = (const float*)d_in[4];
    const float* conv_b = (const float*)d_in[5];
    const float* Wk     = (const float*)d_in[6];
    const float* Wks    = (const float*)d_in[8];
    const float* Wv     = (const float*)d_in[10];
    const float* bv     = (const float*)d_in[11];
    const float* Wvs    = (const float*)d_in[12];
    const float* a1     = (const float*)d_in[14];
    const float* a1b    = (const float*)d_in[15];
    const float* a2     = (const float*)d_in[16];
    const float* a2b    = (const float*)d_in[17];
    const float* a3     = (const float*)d_in[18];
    const float* a3b    = (const float*)d_in[19];
    const float* v1     = (const float*)d_in[20];
    const float* v1b    = (const float*)d_in[21];
    const float* v2     = (const float*)d_in[22];
    const float* v2b    = (const float*)d_in[23];
    const float* v3     = (const float*)d_in[24];
    const float* v3b    = (const float*)d_in[25];
    (void)in_sizes; (void)n_in; (void)out_size; (void)ws_size;

    float* ws  = (float*)d_ws;
    float* RD  = ws + OFF_RD;
    float* bvW2= RD + 25 * 768;
    int*   FL  = (int*)(ws + OFF_FL);
    float* DT  = ws + OFF_DT;
    short* WCT = (short*)(ws + OFF_WCT);
    short* PH  = (short*)(ws + OFF_PH);
    short* AB  = (short*)(ws + OFF_AB);
    short* XKH = (short*)(ws + OFF_XKH);
    short* XVH = (short*)(ws + OFF_XVH);
    short* VWH = (short*)(ws + OFF_VWH);
    short* YH  = (short*)(ws + OFF_YH);
    float* PART= ws + OFF_PART;
    float* out = (float*)d_out;

    // 1) single-pass temb (read once, bf16 LDS) + all prep incl. fp32 WCT
    k1_fused<<<NBS + 546, 512, 0, stream>>>(
        temb, Wks, Wvs, conv_w, sprite, Wk, Wv, bv, a1, v1,
        XKH, XVH, AB, PH, WCT, RD, FL);
    // 2) VWH = XVH@WCT^T + bv@W2 (bf16)  ||  DT = XKH@PH^T (fp32)
    k3_vwdt<<<dim3(24,13,1),256,0,stream>>>(XVH, WCT, bvW2, VWH, XKH, PH, DT);
    // 3) conv + flatten
    k4_y<<<BS, 512, 0, stream>>>(state, DT, FL, VWH, RD, conv_b, YH);
    // 4) layer-1 split-K GEMM
    gemm_mfma<0,0><<<dim3(8,4,KSPLIT),256,0,stream>>>(YH, AB, nullptr, PART, 5184, 256, KCH, (size_t)BS*256);
    // 5) reduce + heads
    k6_heads<<<BS, 128, 0, stream>>>(PART, a1b, v1b, action, a2, a2b, a3, a3b,
                                     v2, v2b, v3, v3b, out);
}